// Round 4
// baseline (711.574 us; speedup 1.0000x reference)
//
#include <hip/hip_runtime.h>

typedef float f32x4 __attribute__((ext_vector_type(4)));
typedef float f32x2 __attribute__((ext_vector_type(2)));
typedef __bf16 bf16x8 __attribute__((ext_vector_type(8)));
typedef __bf16 bf16x4 __attribute__((ext_vector_type(4)));

__device__ __forceinline__ void gll16(const void* g, void* l) {
  __builtin_amdgcn_global_load_lds(
      (const __attribute__((address_space(1))) uint32_t*)g,
      (__attribute__((address_space(3))) uint32_t*)l, 16, 0, 0);
}

// ---------------------------------------------------------------------------
// GEMM: C = A[M x 512] @ B[512 x N] + bias, B given as BT[N][512] bf16.
// 128x128 tile, BK=64, 4 waves (2x2), global_load_lds staging with XOR chunk
// swizzle on the global source (chunk ^= row&7), same XOR on ds_read_b128.
// QKVOUT=false: C token-major [M][N].
// QKVOUT=true (N=1536): C head-blocked [{q,k,v}*8+h][M][64] so window
//   attention reads are 128B-contiguous per (token, head).
// ---------------------------------------------------------------------------
template<bool QKVOUT>
__global__ __launch_bounds__(256) void gemm_bf16_k512(
    const __bf16* __restrict__ A, const __bf16* __restrict__ BT,
    const float* __restrict__ bias, __bf16* __restrict__ C, int N, int M)
{
  __shared__ __bf16 As[128 * 64];
  __shared__ __bf16 Bs[128 * 64];
  const int tid = threadIdx.x;
  const int wave = tid >> 6, lane = tid & 63;
  const int wr = (wave >> 1) * 64, wc = (wave & 1) * 64;
  const int l15 = lane & 15, l4 = lane >> 4;
  const long arow0 = (long)blockIdx.y * 128;
  const long brow0 = (long)blockIdx.x * 128;

  const int srow = wave * 8 + (lane >> 3);
  const int scp8 = (lane & 7) * 8;

  f32x4 acc[4][4] = {};

  for (int kt = 0; kt < 512; kt += 64) {
    #pragma unroll
    for (int i = 0; i < 4; i++) {
      int row = srow + i * 32;
      int gc = scp8 ^ ((row & 7) * 8);
      gll16(A  + (arow0 + row) * 512 + kt + gc, (char*)As + i * 4096 + wave * 1024);
      gll16(BT + (brow0 + row) * 512 + kt + gc, (char*)Bs + i * 4096 + wave * 1024);
    }
    __syncthreads();
    #pragma unroll
    for (int kk = 0; kk < 2; kk++) {
      bf16x8 af[4], bfr[4];
      #pragma unroll
      for (int m = 0; m < 4; m++) {
        int row = wr + m * 16 + l15;
        int cp8 = ((kk * 4 + l4) * 8) ^ ((row & 7) * 8);
        af[m] = *(const bf16x8*)&As[row * 64 + cp8];
      }
      #pragma unroll
      for (int n = 0; n < 4; n++) {
        int row = wc + n * 16 + l15;
        int cp8 = ((kk * 4 + l4) * 8) ^ ((row & 7) * 8);
        bfr[n] = *(const bf16x8*)&Bs[row * 64 + cp8];
      }
      #pragma unroll
      for (int m = 0; m < 4; m++)
        #pragma unroll
        for (int n = 0; n < 4; n++)
          acc[m][n] = __builtin_amdgcn_mfma_f32_16x16x32_bf16(af[m], bfr[n], acc[m][n], 0, 0, 0);
    }
    __syncthreads();
  }
  // C/D layout: col = lane&15, row = (lane>>4)*4 + i
  #pragma unroll
  for (int n = 0; n < 4; n++) {
    int col = (int)brow0 + wc + n * 16 + l15;
    float bv = bias[col];
    if constexpr (QKVOUT) {
      int s = col >> 9, h = (col >> 6) & 7, d = col & 63;
      __bf16* base = C + ((size_t)(s * 8 + h) * (size_t)M) * 64 + d;
      #pragma unroll
      for (int m = 0; m < 4; m++) {
        long row = arow0 + wr + m * 16 + l4 * 4;
        #pragma unroll
        for (int i = 0; i < 4; i++)
          base[(row + i) * 64] = (__bf16)(acc[m][n][i] + bv);
      }
    } else {
      #pragma unroll
      for (int m = 0; m < 4; m++) {
        long row = arow0 + wr + m * 16 + l4 * 4;
        #pragma unroll
        for (int i = 0; i < 4; i++)
          C[(row + i) * (long)N + col] = (__bf16)(acc[m][n][i] + bv);
      }
    }
  }
}

// ---------------------------------------------------------------------------
// Window attention: 2x2 windows, 8 heads, hd=64. One thread per (window, head).
// QKV in head-blocked layout [{q,k,v}*8+h][M][64] -> each row is a contiguous
// 128B chunk; per-wave working set ~12 KB (L1-resident), no over-fetch.
// Output token-major [M][512].
// ---------------------------------------------------------------------------
__global__ void attn4(const __bf16* __restrict__ qkv, __bf16* __restrict__ o,
                      int M, int nwin, int wg, int Wimg, int wpb, int bst)
{
  int tid = blockIdx.x * 64 + threadIdx.x;
  if (tid >= nwin * 8) return;
  int head = tid & 7;
  int win = tid >> 3;
  int b = win / wpb, wrm = win % wpb;
  int i = wrm / wg, j = wrm % wg;
  int t0 = b * bst + 2 * i * Wimg + 2 * j;
  int trow[4] = { t0, t0 + 1, t0 + Wimg, t0 + Wimg + 1 };

  const __bf16* Qh = qkv + (size_t)head * M * 64;
  const __bf16* Kh = qkv + (size_t)(8 + head) * M * 64;
  const __bf16* Vh = qkv + (size_t)(16 + head) * M * 64;

  float sc[4][4] = {};
  for (int dc = 0; dc < 64; dc += 8) {
    float q[4][8], k[4][8];
    #pragma unroll
    for (int m = 0; m < 4; m++) {
      bf16x8 qv = *(const bf16x8*)(Qh + (long)trow[m] * 64 + dc);
      bf16x8 kv = *(const bf16x8*)(Kh + (long)trow[m] * 64 + dc);
      #pragma unroll
      for (int e = 0; e < 8; e++) { q[m][e] = (float)qv[e]; k[m][e] = (float)kv[e]; }
    }
    #pragma unroll
    for (int m = 0; m < 4; m++)
      #pragma unroll
      for (int n = 0; n < 4; n++) {
        float s = 0.f;
        #pragma unroll
        for (int e = 0; e < 8; e++) s += q[m][e] * k[n][e];
        sc[m][n] += s;
      }
  }
  float attnw[4][4];
  #pragma unroll
  for (int m = 0; m < 4; m++) {
    float v0 = sc[m][0] * 0.125f, v1 = sc[m][1] * 0.125f,
          v2 = sc[m][2] * 0.125f, v3 = sc[m][3] * 0.125f;
    float mx = fmaxf(fmaxf(v0, v1), fmaxf(v2, v3));
    float e0 = __expf(v0 - mx), e1 = __expf(v1 - mx), e2 = __expf(v2 - mx), e3 = __expf(v3 - mx);
    float inv = 1.f / (e0 + e1 + e2 + e3);
    attnw[m][0] = e0 * inv; attnw[m][1] = e1 * inv; attnw[m][2] = e2 * inv; attnw[m][3] = e3 * inv;
  }
  const int co = head * 64;
  for (int dc = 0; dc < 64; dc += 8) {
    float v[4][8];
    #pragma unroll
    for (int n = 0; n < 4; n++) {
      bf16x8 vv = *(const bf16x8*)(Vh + (long)trow[n] * 64 + dc);
      #pragma unroll
      for (int e = 0; e < 8; e++) v[n][e] = (float)vv[e];
    }
    #pragma unroll
    for (int m = 0; m < 4; m++) {
      bf16x8 ov;
      #pragma unroll
      for (int e = 0; e < 8; e++) {
        float s = attnw[m][0] * v[0][e] + attnw[m][1] * v[1][e]
                + attnw[m][2] * v[2][e] + attnw[m][3] * v[3][e];
        ov[e] = (__bf16)s;
      }
      *(bf16x8*)(o + (long)trow[m] * 512 + co + dc) = ov;
    }
  }
}

// Transpose + fp32->bf16: out[N][K] = (bf16) in[K][N]
__global__ __launch_bounds__(256) void transpose_f32_bf16(
    const float* __restrict__ in, __bf16* __restrict__ out, int K, int N)
{
  __shared__ float t[64][65];
  int n0 = blockIdx.x * 64, k0 = blockIdx.y * 64;
  int tid = threadIdx.x;
  int nl4 = (tid & 15) * 4, kl = tid >> 4;
  #pragma unroll
  for (int p = 0; p < 4; p++) {
    int kk = kl + p * 16;
    f32x4 v = *(const f32x4*)(in + (long)(k0 + kk) * N + n0 + nl4);
    t[kk][nl4 + 0] = v.x; t[kk][nl4 + 1] = v.y; t[kk][nl4 + 2] = v.z; t[kk][nl4 + 3] = v.w;
  }
  __syncthreads();
  int ks = tid & 63, wv = tid >> 6;
  #pragma unroll
  for (int p = 0; p < 16; p++) {
    int nn = wv * 16 + p;
    out[(long)(n0 + nn) * K + k0 + ks] = (__bf16)t[ks][nn];
  }
}

// Fused: Xbf = bf16(x) (flat) AND P = AvgPool2d(2) of x viewed (B,C,128,128).
__global__ __launch_bounds__(256) void convpool(const float* __restrict__ x,
    __bf16* __restrict__ Xbf, __bf16* __restrict__ P)
{
  int t = blockIdx.x * 256 + threadIdx.x;   // 2,097,152 threads
  int j8 = (t & 15) * 8;
  int i2 = (t >> 4) & 63;
  long bc = t >> 10;
  const float* r0 = x + bc * 16384 + (2 * i2) * 128 + j8;
  f32x4 a0 = *(const f32x4*)r0,         a1 = *(const f32x4*)(r0 + 4);
  f32x4 b0 = *(const f32x4*)(r0 + 128), b1 = *(const f32x4*)(r0 + 132);
  bf16x8 xa, xb;
  xa[0] = (__bf16)a0.x; xa[1] = (__bf16)a0.y; xa[2] = (__bf16)a0.z; xa[3] = (__bf16)a0.w;
  xa[4] = (__bf16)a1.x; xa[5] = (__bf16)a1.y; xa[6] = (__bf16)a1.z; xa[7] = (__bf16)a1.w;
  xb[0] = (__bf16)b0.x; xb[1] = (__bf16)b0.y; xb[2] = (__bf16)b0.z; xb[3] = (__bf16)b0.w;
  xb[4] = (__bf16)b1.x; xb[5] = (__bf16)b1.y; xb[6] = (__bf16)b1.z; xb[7] = (__bf16)b1.w;
  *(bf16x8*)(Xbf + bc * 16384 + (2 * i2) * 128 + j8) = xa;
  *(bf16x8*)(Xbf + bc * 16384 + (2 * i2) * 128 + 128 + j8) = xb;
  bf16x4 p;
  p[0] = (__bf16)((a0.x + a0.y + b0.x + b0.y) * 0.25f);
  p[1] = (__bf16)((a0.z + a0.w + b0.z + b0.w) * 0.25f);
  p[2] = (__bf16)((a1.x + a1.y + b1.x + b1.y) * 0.25f);
  p[3] = (__bf16)((a1.z + a1.w + b1.z + b1.w) * 0.25f);
  *(bf16x4*)(P + bc * 4096 + i2 * 64 + (t & 15) * 4) = p;
}

// s = lx + ly stencil on O_l viewed as (B,C,64,64); reflect pad baked in.
__global__ void skern(const __bf16* __restrict__ l, float* __restrict__ s)
{
  int tid = blockIdx.x * 256 + threadIdx.x;   // 8388608
  int j = tid & 63, i = (tid >> 6) & 63;
  long bc = tid >> 12;
  const __bf16* base = l + bc * 4096;
  int im1 = (i == 0) ? 1 : i - 1;
  int jp1 = (j == 63) ? 62 : j + 1;
  float v = 0.5f * (float)base[im1 * 64 + j] + (float)base[i * 64 + j]
          + 0.5f * (float)base[i * 64 + jp1];
  s[tid] = v;
}

// Final: out(B,C,H,W) = G + bilinear_up2(S), LDS-staged S pair + LDS transpose,
// f32x4 vectorized stores.
__global__ __launch_bounds__(256) void final_v2(
    const __bf16* __restrict__ G, const float* __restrict__ S, float* __restrict__ out)
{
  __shared__ float Sl[8192];
  __shared__ float t[64][65];
  int b = blockIdx.z;
  int p0 = blockIdx.y * 64, c0 = blockIdx.x * 64;
  int tid = threadIdx.x;

  int k2 = blockIdx.y;                 // (p0*512 + c0) >> 15
  const float* Sb = S + (long)b * 2097152 + (long)k2 * 8192;
  #pragma unroll
  for (int i = 0; i < 8; i++)
    *(f32x4*)&Sl[i * 1024 + tid * 4] = *(const f32x4*)(Sb + i * 1024 + tid * 4);
  __syncthreads();

  int cl4 = (tid & 15) * 4, pl = tid >> 4;
  const __bf16* Gb = G + ((long)b * 16384 + p0) * 512 + c0;
  #pragma unroll
  for (int q2 = 0; q2 < 4; q2++) {
    int pp = pl + q2 * 16;
    bf16x4 g = *(const bf16x4*)(Gb + (long)pp * 512 + cl4);
    int qbase = (p0 + pp) * 512 + c0 + cl4;
    #pragma unroll
    for (int e = 0; e < 4; e++) {
      int q = qbase + e;
      int lc = (q >> 14) & 1;
      int r = q & 16383, hh = r >> 7, ww = r & 127;
      const float* sb = Sl + lc * 4096;
      int i0, i1, j0, j1; float wi0, wi1, wj0, wj1;
      if (hh & 1) { i0 = hh >> 1; i1 = (i0 < 63) ? i0 + 1 : 63; wi0 = 0.75f; wi1 = 0.25f; }
      else        { i1 = hh >> 1; i0 = (i1 > 0) ? i1 - 1 : 0;   wi0 = 0.25f; wi1 = 0.75f; }
      if (ww & 1) { j0 = ww >> 1; j1 = (j0 < 63) ? j0 + 1 : 63; wj0 = 0.75f; wj1 = 0.25f; }
      else        { j1 = ww >> 1; j0 = (j1 > 0) ? j1 - 1 : 0;   wj0 = 0.25f; wj1 = 0.75f; }
      float up = wi0 * (wj0 * sb[i0 * 64 + j0] + wj1 * sb[i0 * 64 + j1])
               + wi1 * (wj0 * sb[i1 * 64 + j0] + wj1 * sb[i1 * 64 + j1]);
      t[pp][cl4 + e] = (float)g[e] + up;
    }
  }
  __syncthreads();
  int l15b = tid & 15, hi = (tid >> 4) & 3, wv = tid >> 6;
  float* ob = out + (long)b * 8388608 + (long)c0 * 16384 + p0;
  #pragma unroll
  for (int it = 0; it < 4; it++) {
    int cc = wv * 16 + it * 4 + hi;
    f32x4 v;
    v.x = t[l15b * 4 + 0][cc]; v.y = t[l15b * 4 + 1][cc];
    v.z = t[l15b * 4 + 2][cc]; v.w = t[l15b * 4 + 3][cc];
    *(f32x4*)(ob + (long)cc * 16384 + l15b * 4) = v;
  }
}

// ---------------------------------------------------------------------------
extern "C" void kernel_launch(void* const* d_in, const int* in_sizes, int n_in,
                              void* d_out, int out_size, void* d_ws, size_t ws_size,
                              hipStream_t stream)
{
  const float* x     = (const float*)d_in[0];
  const float* Wqkv  = (const float*)d_in[1];
  const float* bqkv  = (const float*)d_in[2];
  const float* Wproj = (const float*)d_in[3];
  const float* bproj = (const float*)d_in[4];
  float* out = (float*)d_out;

  char* w = (char*)d_ws;
  __bf16* WqkvT  = (__bf16*)w;  w += (size_t)1536 * 512 * 2;
  __bf16* WprojT = (__bf16*)w;  w += (size_t)512 * 512 * 2;
  __bf16* Xbf    = (__bf16*)w;  w += (size_t)65536 * 512 * 2;   // aliased as G
  __bf16* G      = Xbf;
  __bf16* P      = (__bf16*)w;  w += (size_t)2048 * 4096 * 2;

  bool batched = ws_size >= ((size_t)356 << 20);
  size_t mchunk = batched ? 65536 : 16384;
  __bf16* QKVbuf = (__bf16*)w;  w += mchunk * 1536 * 2;
  __bf16* Obuf   = (__bf16*)w;
  float*  S      = (float*)QKVbuf;   // QKV dead when S is produced

  transpose_f32_bf16<<<dim3(24, 8), 256, 0, stream>>>(Wqkv, WqkvT, 512, 1536);
  transpose_f32_bf16<<<dim3(8, 8), 256, 0, stream>>>(Wproj, WprojT, 512, 512);
  convpool<<<8192, 256, 0, stream>>>(x, Xbf, P);

  int nch = batched ? 1 : 4;
  int mrows = (int)mchunk;
  for (int c = 0; c < nch; c++) {
    const __bf16* Ac = Xbf + (size_t)c * 16384 * 512;
    gemm_bf16_k512<true><<<dim3(12, mrows / 128), 256, 0, stream>>>(
        Ac, WqkvT, bqkv, QKVbuf, 1536, mrows);
    attn4<<<(mrows / 4) * 8 / 64, 64, 0, stream>>>(
        QKVbuf, Obuf, mrows, mrows / 4, 64, 128, 4096, 16384);
    gemm_bf16_k512<false><<<dim3(4, mrows / 128), 256, 0, stream>>>(
        Obuf, WprojT, bproj, G + (size_t)c * 16384 * 512, 512, mrows);
  }

  // local path
  gemm_bf16_k512<true><<<dim3(12, 128), 256, 0, stream>>>(
      P, WqkvT, bqkv, QKVbuf, 1536, 16384);
  attn4<<<512, 64, 0, stream>>>(QKVbuf, Obuf, 16384, 4096, 32, 64, 1024, 4096);
  skern<<<8388608 / 256, 256, 0, stream>>>(Obuf, S);

  final_v2<<<dim3(8, 256, 4), 256, 0, stream>>>(G, S, out);
}

// Round 6
// 481.144 us; speedup vs baseline: 1.4789x; 1.4789x over previous
//
#include <hip/hip_runtime.h>

typedef float f32x4 __attribute__((ext_vector_type(4)));
typedef float f32x2 __attribute__((ext_vector_type(2)));
typedef __bf16 bf16x8 __attribute__((ext_vector_type(8)));
typedef __bf16 bf16x4 __attribute__((ext_vector_type(4)));

__device__ __forceinline__ void gll16(const void* g, void* l) {
  __builtin_amdgcn_global_load_lds(
      (const __attribute__((address_space(1))) uint32_t*)g,
      (__attribute__((address_space(3))) uint32_t*)l, 16, 0, 0);
}

// ---------------------------------------------------------------------------
// GEMM: C[M x N] bf16 = A[M x 512] @ B[512 x N] + bias, B as BT[N][512] bf16.
// 128x128 tile, BK=64, 4 waves (2x2). global_load_lds direct staging with
// XOR chunk swizzle (chunk ^= row&7) on the global source address;
// ds_read_b128 fragment reads use the same XOR -> conflict-free.
// ---------------------------------------------------------------------------
__global__ __launch_bounds__(256) void gemm_bf16_k512(
    const __bf16* __restrict__ A, const __bf16* __restrict__ BT,
    const float* __restrict__ bias, __bf16* __restrict__ C, int N)
{
  __shared__ __bf16 As[128 * 64];
  __shared__ __bf16 Bs[128 * 64];
  const int tid = threadIdx.x;
  const int wave = tid >> 6, lane = tid & 63;
  const int wr = (wave >> 1) * 64, wc = (wave & 1) * 64;
  const int l15 = lane & 15, l4 = lane >> 4;
  const long arow0 = (long)blockIdx.y * 128;
  const long brow0 = (long)blockIdx.x * 128;

  const int srow = wave * 8 + (lane >> 3);
  const int scp8 = (lane & 7) * 8;

  f32x4 acc[4][4] = {};

  for (int kt = 0; kt < 512; kt += 64) {
    #pragma unroll
    for (int i = 0; i < 4; i++) {
      int row = srow + i * 32;
      int gc = scp8 ^ ((row & 7) * 8);
      gll16(A  + (arow0 + row) * 512 + kt + gc, (char*)As + i * 4096 + wave * 1024);
      gll16(BT + (brow0 + row) * 512 + kt + gc, (char*)Bs + i * 4096 + wave * 1024);
    }
    __syncthreads();
    #pragma unroll
    for (int kk = 0; kk < 2; kk++) {
      bf16x8 af[4], bfr[4];
      #pragma unroll
      for (int m = 0; m < 4; m++) {
        int row = wr + m * 16 + l15;
        int cp8 = ((kk * 4 + l4) * 8) ^ ((row & 7) * 8);
        af[m] = *(const bf16x8*)&As[row * 64 + cp8];
      }
      #pragma unroll
      for (int n = 0; n < 4; n++) {
        int row = wc + n * 16 + l15;
        int cp8 = ((kk * 4 + l4) * 8) ^ ((row & 7) * 8);
        bfr[n] = *(const bf16x8*)&Bs[row * 64 + cp8];
      }
      #pragma unroll
      for (int m = 0; m < 4; m++)
        #pragma unroll
        for (int n = 0; n < 4; n++)
          acc[m][n] = __builtin_amdgcn_mfma_f32_16x16x32_bf16(af[m], bfr[n], acc[m][n], 0, 0, 0);
    }
    __syncthreads();
  }
  // C/D layout: col = lane&15, row = (lane>>4)*4 + i
  #pragma unroll
  for (int n = 0; n < 4; n++) {
    int col = (int)brow0 + wc + n * 16 + l15;
    float bv = bias[col];
    #pragma unroll
    for (int m = 0; m < 4; m++) {
      long row = arow0 + wr + m * 16 + l4 * 4;
      #pragma unroll
      for (int i = 0; i < 4; i++)
        C[(row + i) * (long)N + col] = (__bf16)(acc[m][n][i] + bv);
    }
  }
}

// ---------------------------------------------------------------------------
// Window attention v3: 2x2 windows, 8 heads, hd=64.
// 4 threads per (window, head) -- one per query token. Each thread consumes
// full 128B QKV rows with back-to-back 16B loads (no partial-line eviction);
// the 4 lanes of a group read identical K/V addresses (L1 broadcast).
// qkv token-major [M][1536]; output token-major [M][512].
// ---------------------------------------------------------------------------
__global__ __launch_bounds__(256) void attn4(
    const __bf16* __restrict__ qkv, __bf16* __restrict__ o,
    int nwin, int wg, int Wimg, int wpb, int bst)
{
  int tid = blockIdx.x * 256 + threadIdx.x;
  int m = tid & 3;
  int head = (tid >> 2) & 7;
  int win = tid >> 5;
  if (win >= nwin) return;
  int b = win / wpb, wrm = win % wpb;
  int i = wrm / wg, j = wrm % wg;
  int t0 = b * bst + 2 * i * Wimg + 2 * j;
  int tn[4] = { t0, t0 + 1, t0 + Wimg, t0 + Wimg + 1 };
  int trow = tn[m];
  const int co = head * 64;

  // my Q row, fully loaded then converted
  float qf[64];
  #pragma unroll
  for (int c = 0; c < 8; c++) {
    bf16x8 v = *(const bf16x8*)(qkv + (long)trow * 1536 + co + c * 8);
    #pragma unroll
    for (int e = 0; e < 8; e++) qf[c * 8 + e] = (float)v[e];
  }

  // stream K rows (group-shared addresses)
  float s[4];
  #pragma unroll
  for (int n = 0; n < 4; n++) {
    float acc = 0.f;
    #pragma unroll
    for (int c = 0; c < 8; c++) {
      bf16x8 kv = *(const bf16x8*)(qkv + (long)tn[n] * 1536 + 512 + co + c * 8);
      #pragma unroll
      for (int e = 0; e < 8; e++) acc += qf[c * 8 + e] * (float)kv[e];
    }
    s[n] = acc * 0.125f;
  }

  float mx = fmaxf(fmaxf(s[0], s[1]), fmaxf(s[2], s[3]));
  float e0 = __expf(s[0] - mx), e1 = __expf(s[1] - mx),
        e2 = __expf(s[2] - mx), e3 = __expf(s[3] - mx);
  float inv = 1.f / (e0 + e1 + e2 + e3);
  float w4[4] = { e0 * inv, e1 * inv, e2 * inv, e3 * inv };

  // stream V rows, accumulate output
  float of[64] = {};
  #pragma unroll
  for (int n = 0; n < 4; n++) {
    float wn = w4[n];
    #pragma unroll
    for (int c = 0; c < 8; c++) {
      bf16x8 vv = *(const bf16x8*)(qkv + (long)tn[n] * 1536 + 1024 + co + c * 8);
      #pragma unroll
      for (int e = 0; e < 8; e++) of[c * 8 + e] += wn * (float)vv[e];
    }
  }

  #pragma unroll
  for (int c = 0; c < 8; c++) {
    bf16x8 ov;
    #pragma unroll
    for (int e = 0; e < 8; e++) ov[e] = (__bf16)of[c * 8 + e];
    *(bf16x8*)(o + (long)trow * 512 + co + c * 8) = ov;
  }
}

// Transpose + fp32->bf16: out[N][K] = (bf16) in[K][N]
__global__ __launch_bounds__(256) void transpose_f32_bf16(
    const float* __restrict__ in, __bf16* __restrict__ out, int K, int N)
{
  __shared__ float t[64][65];
  int n0 = blockIdx.x * 64, k0 = blockIdx.y * 64;
  int tid = threadIdx.x;
  int nl4 = (tid & 15) * 4, kl = tid >> 4;
  #pragma unroll
  for (int p = 0; p < 4; p++) {
    int kk = kl + p * 16;
    f32x4 v = *(const f32x4*)(in + (long)(k0 + kk) * N + n0 + nl4);
    t[kk][nl4 + 0] = v.x; t[kk][nl4 + 1] = v.y; t[kk][nl4 + 2] = v.z; t[kk][nl4 + 3] = v.w;
  }
  __syncthreads();
  int ks = tid & 63, wv = tid >> 6;
  #pragma unroll
  for (int p = 0; p < 16; p++) {
    int nn = wv * 16 + p;
    out[(long)(n0 + nn) * K + k0 + ks] = (__bf16)t[ks][nn];
  }
}

// Fused: Xbf = bf16(x) (flat) AND P = AvgPool2d(2) of x viewed (B,C,128,128).
__global__ __launch_bounds__(256) void convpool(const float* __restrict__ x,
    __bf16* __restrict__ Xbf, __bf16* __restrict__ P)
{
  int t = blockIdx.x * 256 + threadIdx.x;   // 2,097,152 threads
  int j8 = (t & 15) * 8;
  int i2 = (t >> 4) & 63;
  long bc = t >> 10;
  const float* r0 = x + bc * 16384 + (2 * i2) * 128 + j8;
  f32x4 a0 = *(const f32x4*)r0,         a1 = *(const f32x4*)(r0 + 4);
  f32x4 b0 = *(const f32x4*)(r0 + 128), b1 = *(const f32x4*)(r0 + 132);
  bf16x8 xa, xb;
  xa[0] = (__bf16)a0.x; xa[1] = (__bf16)a0.y; xa[2] = (__bf16)a0.z; xa[3] = (__bf16)a0.w;
  xa[4] = (__bf16)a1.x; xa[5] = (__bf16)a1.y; xa[6] = (__bf16)a1.z; xa[7] = (__bf16)a1.w;
  xb[0] = (__bf16)b0.x; xb[1] = (__bf16)b0.y; xb[2] = (__bf16)b0.z; xb[3] = (__bf16)b0.w;
  xb[4] = (__bf16)b1.x; xb[5] = (__bf16)b1.y; xb[6] = (__bf16)b1.z; xb[7] = (__bf16)b1.w;
  *(bf16x8*)(Xbf + bc * 16384 + (2 * i2) * 128 + j8) = xa;
  *(bf16x8*)(Xbf + bc * 16384 + (2 * i2) * 128 + 128 + j8) = xb;
  bf16x4 p;
  p[0] = (__bf16)((a0.x + a0.y + b0.x + b0.y) * 0.25f);
  p[1] = (__bf16)((a0.z + a0.w + b0.z + b0.w) * 0.25f);
  p[2] = (__bf16)((a1.x + a1.y + b1.x + b1.y) * 0.25f);
  p[3] = (__bf16)((a1.z + a1.w + b1.z + b1.w) * 0.25f);
  *(bf16x4*)(P + bc * 4096 + i2 * 64 + (t & 15) * 4) = p;
}

// s = lx + ly stencil on O_l viewed as (B,C,64,64); reflect pad baked in.
__global__ void skern(const __bf16* __restrict__ l, float* __restrict__ s)
{
  int tid = blockIdx.x * 256 + threadIdx.x;   // 8388608
  int j = tid & 63, i = (tid >> 6) & 63;
  long bc = tid >> 12;
  const __bf16* base = l + bc * 4096;
  int im1 = (i == 0) ? 1 : i - 1;
  int jp1 = (j == 63) ? 62 : j + 1;
  float v = 0.5f * (float)base[im1 * 64 + j] + (float)base[i * 64 + j]
          + 0.5f * (float)base[i * 64 + jp1];
  s[tid] = v;
}

// Final: out(B,C,H,W) = G + bilinear_up2(S), LDS-staged S pair + LDS transpose,
// f32x4 vectorized stores.
__global__ __launch_bounds__(256) void final_v2(
    const __bf16* __restrict__ G, const float* __restrict__ S, float* __restrict__ out)
{
  __shared__ float Sl[8192];
  __shared__ float t[64][65];
  int b = blockIdx.z;
  int p0 = blockIdx.y * 64, c0 = blockIdx.x * 64;
  int tid = threadIdx.x;

  int k2 = blockIdx.y;                 // (p0*512 + c0) >> 15
  const float* Sb = S + (long)b * 2097152 + (long)k2 * 8192;
  #pragma unroll
  for (int i = 0; i < 8; i++)
    *(f32x4*)&Sl[i * 1024 + tid * 4] = *(const f32x4*)(Sb + i * 1024 + tid * 4);
  __syncthreads();

  int cl4 = (tid & 15) * 4, pl = tid >> 4;
  const __bf16* Gb = G + ((long)b * 16384 + p0) * 512 + c0;
  #pragma unroll
  for (int q2 = 0; q2 < 4; q2++) {
    int pp = pl + q2 * 16;
    bf16x4 g = *(const bf16x4*)(Gb + (long)pp * 512 + cl4);
    int qbase = (p0 + pp) * 512 + c0 + cl4;
    #pragma unroll
    for (int e = 0; e < 4; e++) {
      int q = qbase + e;
      int lc = (q >> 14) & 1;
      int r = q & 16383, hh = r >> 7, ww = r & 127;
      const float* sb = Sl + lc * 4096;
      int i0, i1, j0, j1; float wi0, wi1, wj0, wj1;
      if (hh & 1) { i0 = hh >> 1; i1 = (i0 < 63) ? i0 + 1 : 63; wi0 = 0.75f; wi1 = 0.25f; }
      else        { i1 = hh >> 1; i0 = (i1 > 0) ? i1 - 1 : 0;   wi0 = 0.25f; wi1 = 0.75f; }
      if (ww & 1) { j0 = ww >> 1; j1 = (j0 < 63) ? j0 + 1 : 63; wj0 = 0.75f; wj1 = 0.25f; }
      else        { j1 = ww >> 1; j0 = (j1 > 0) ? j1 - 1 : 0;   wj0 = 0.25f; wj1 = 0.75f; }
      float up = wi0 * (wj0 * sb[i0 * 64 + j0] + wj1 * sb[i0 * 64 + j1])
               + wi1 * (wj0 * sb[i1 * 64 + j0] + wj1 * sb[i1 * 64 + j1]);
      t[pp][cl4 + e] = (float)g[e] + up;
    }
  }
  __syncthreads();
  int l15b = tid & 15, hi = (tid >> 4) & 3, wv = tid >> 6;
  float* ob = out + (long)b * 8388608 + (long)c0 * 16384 + p0;
  #pragma unroll
  for (int it = 0; it < 4; it++) {
    int cc = wv * 16 + it * 4 + hi;
    f32x4 v;
    v.x = t[l15b * 4 + 0][cc]; v.y = t[l15b * 4 + 1][cc];
    v.z = t[l15b * 4 + 2][cc]; v.w = t[l15b * 4 + 3][cc];
    *(f32x4*)(ob + (long)cc * 16384 + l15b * 4) = v;
  }
}

// ---------------------------------------------------------------------------
extern "C" void kernel_launch(void* const* d_in, const int* in_sizes, int n_in,
                              void* d_out, int out_size, void* d_ws, size_t ws_size,
                              hipStream_t stream)
{
  const float* x     = (const float*)d_in[0];
  const float* Wqkv  = (const float*)d_in[1];
  const float* bqkv  = (const float*)d_in[2];
  const float* Wproj = (const float*)d_in[3];
  const float* bproj = (const float*)d_in[4];
  float* out = (float*)d_out;

  char* w = (char*)d_ws;
  __bf16* WqkvT  = (__bf16*)w;  w += (size_t)1536 * 512 * 2;
  __bf16* WprojT = (__bf16*)w;  w += (size_t)512 * 512 * 2;
  __bf16* Xbf    = (__bf16*)w;  w += (size_t)65536 * 512 * 2;   // aliased as G
  __bf16* G      = Xbf;
  __bf16* P      = (__bf16*)w;  w += (size_t)2048 * 4096 * 2;

  bool batched = ws_size >= ((size_t)356 << 20);
  size_t mchunk = batched ? 65536 : 16384;
  __bf16* QKVbuf = (__bf16*)w;  w += mchunk * 1536 * 2;
  __bf16* Obuf   = (__bf16*)w;
  float*  S      = (float*)QKVbuf;   // QKV dead when S is produced

  transpose_f32_bf16<<<dim3(24, 8), 256, 0, stream>>>(Wqkv, WqkvT, 512, 1536);
  transpose_f32_bf16<<<dim3(8, 8), 256, 0, stream>>>(Wproj, WprojT, 512, 512);
  convpool<<<8192, 256, 0, stream>>>(x, Xbf, P);

  int nch = batched ? 1 : 4;
  int mrows = (int)mchunk;
  for (int c = 0; c < nch; c++) {
    const __bf16* Ac = Xbf + (size_t)c * 16384 * 512;
    gemm_bf16_k512<<<dim3(12, mrows / 128), 256, 0, stream>>>(Ac, WqkvT, bqkv, QKVbuf, 1536);
    // 4 threads per (window, head): nwin*32 threads
    attn4<<<(mrows / 4) * 32 / 256, 256, 0, stream>>>(
        QKVbuf, Obuf, mrows / 4, 64, 128, 4096, 16384);
    gemm_bf16_k512<<<dim3(4, mrows / 128), 256, 0, stream>>>(Obuf, WprojT, bproj,
                                                             G + (size_t)c * 16384 * 512, 512);
  }

  // local path
  gemm_bf16_k512<<<dim3(12, 128), 256, 0, stream>>>(P, WqkvT, bqkv, QKVbuf, 1536);
  attn4<<<512, 256, 0, stream>>>(QKVbuf, Obuf, 4096, 32, 64, 1024, 4096);
  skern<<<8388608 / 256, 256, 0, stream>>>(Obuf, S);

  final_v2<<<dim3(8, 256, 4), 256, 0, stream>>>(G, S, out);
}